// Round 5
// baseline (794.019 us; speedup 1.0000x reference)
//
#include <hip/hip_runtime.h>

// ---------------- problem constants ----------------
constexpr int Bb = 2;
constexpr int Ss = 256;
constexpr int Dd = 512;
constexpr int Vv = 32000;
constexpr int NVB = Vv / 64;          // 500 v-bands
constexpr float GAMMA_C = 2.0f;
constexpr int MEMLEN = 16;
constexpr int NMEM = 256;
constexpr int MTOT = (8 + 4) * MEMLEN;   // 192
constexpr int CTXROWS = MTOT + Ss;       // 448

// output layout (floats)
constexpr size_t NQ   = (size_t)Bb * Ss * Dd;        // 262144
constexpr size_t OC1  = NQ;                          // 262144
constexpr size_t NCTX = (size_t)Bb * CTXROWS * Dd;   // 458752
constexpr size_t OC2  = OC1 + NCTX;                  // 720896
constexpr size_t OMASK = OC2 + NCTX;                 // 1179648

// workspace layout (floats); total ≈ 3.67 MB
constexpr size_t WS_FLOATS_NEEDED = 256000 + 512 + 512 + 131072 + 131584 + 512 +
                                    1024 + 1024 + 512 + 196608 + 196608 + 4096;

// ---------------- shared 64x64 fp32 GEMM core (K=512, lda=ldb=512) ----------------
// acc[i][j] = sum_k A[tm*4+i][k] * B[tn*4+j][k]   (A,B row-major, 512 cols)
__device__ __forceinline__ void gemm64x64_k512(const float* __restrict__ A,
                                               const float* __restrict__ Bm,
                                               float acc[4][4],
                                               float* __restrict__ Qs,
                                               float* __restrict__ Ws) {
  const int t = threadIdx.x;
  const int tn = t & 15, tm = t >> 4;
  #pragma unroll 1
  for (int kc = 0; kc < 512; kc += 32) {
    #pragma unroll
    for (int e = 0; e < 2; ++e) {
      int idx4 = t + 256 * e;          // 0..511
      int m = idx4 >> 3;               // 0..63
      int k4 = (idx4 & 7) << 2;        // 0..28
      const float4 qa = *(const float4*)(A + (size_t)m * 512 + kc + k4);
      const float4 wb = *(const float4*)(Bm + (size_t)m * 512 + kc + k4);
      Qs[(k4 + 0) * 68 + m] = qa.x; Qs[(k4 + 1) * 68 + m] = qa.y;
      Qs[(k4 + 2) * 68 + m] = qa.z; Qs[(k4 + 3) * 68 + m] = qa.w;
      Ws[(k4 + 0) * 68 + m] = wb.x; Ws[(k4 + 1) * 68 + m] = wb.y;
      Ws[(k4 + 2) * 68 + m] = wb.z; Ws[(k4 + 3) * 68 + m] = wb.w;
    }
    __syncthreads();
    #pragma unroll
    for (int k = 0; k < 32; ++k) {
      const float4 a4 = *(const float4*)(Qs + k * 68 + (tm << 2));
      const float4 b4 = *(const float4*)(Ws + k * 68 + (tn << 2));
      const float av[4] = {a4.x, a4.y, a4.z, a4.w};
      const float bv[4] = {b4.x, b4.y, b4.z, b4.w};
      #pragma unroll
      for (int i = 0; i < 4; ++i)
        #pragma unroll
        for (int j = 0; j < 4; ++j)
          acc[i][j] += av[i] * bv[j];
    }
    __syncthreads();
  }
}

// ---------------- 1) logits tile + per-row band sum(exp(z)) ----------------
__global__ __launch_bounds__(256) void k_logits(const float* __restrict__ q,
                                                const float* __restrict__ bw,
                                                float* __restrict__ partial) {
  __shared__ float Qs[32 * 68];
  __shared__ float Ws[32 * 68];
  __shared__ float red[64 * 17];
  const int bv = blockIdx.x;   // 0..499
  const int bm = blockIdx.y;   // 0..7
  float acc[4][4] = {};
  gemm64x64_k512(q + (size_t)bm * 64 * 512, bw + (size_t)bv * 64 * 512, acc, Qs, Ws);
  const int t = threadIdx.x, tn = t & 15, tm = t >> 4;
  #pragma unroll
  for (int i = 0; i < 4; ++i) {
    float s = 0.f;
    #pragma unroll
    for (int j = 0; j < 4; ++j) s += expf(acc[i][j]);
    red[(tm * 4 + i) * 17 + tn] = s;
  }
  __syncthreads();
  if (t < 64) {
    float s = 0.f;
    #pragma unroll
    for (int j = 0; j < 16; ++j) s += red[t * 17 + j];
    partial[(size_t)bv * 512 + bm * 64 + t] = s;   // [band][row] for coalesced combine
  }
}

// ---------------- 2) combine partials -> lse ----------------
__global__ __launch_bounds__(256) void k_lse(const float* __restrict__ partial,
                                             float* __restrict__ lse) {
  int r = blockIdx.x * 256 + threadIdx.x;   // 0..511
  double s = 0.0;
  for (int j = 0; j < NVB; ++j) s += (double)partial[(size_t)j * 512 + r];
  lse[r] = (float)log(s);
}

// ---------------- 3) z_target, surprise = lse - z_target ----------------
__global__ __launch_bounds__(256) void k_zt(const float* __restrict__ q,
                                            const float* __restrict__ bw,
                                            const int* __restrict__ tgt,
                                            const float* __restrict__ lse,
                                            float* __restrict__ sur) {
  int wid = blockIdx.x * 4 + (threadIdx.x >> 6);  // 0..511
  int lane = threadIdx.x & 63;
  int tg = tgt[wid];
  const float* qp = q + (size_t)wid * 512;
  const float* wp = bw + (size_t)tg * 512;
  float a = 0.f;
  #pragma unroll
  for (int j = 0; j < 8; ++j) a += qp[lane + 64 * j] * wp[lane + 64 * j];
  #pragma unroll
  for (int off = 32; off; off >>= 1) a += __shfl_xor(a, off);
  if (lane == 0) sur[wid] = lse[wid] - a;
}

// ---------------- 4) windowed threshold -> boundaries ----------------
__global__ __launch_bounds__(256) void k_bound(const float* __restrict__ sur,
                                               int* __restrict__ bnd) {
  __shared__ float ss[256];
  __shared__ float thrw[237];
  int b = blockIdx.x, t = threadIdx.x;
  ss[t] = sur[b * 256 + t];
  __syncthreads();
  if (t < 237) {
    float mn = 0.f;
    #pragma unroll
    for (int e = 0; e < 20; ++e) mn += ss[t + e];
    mn *= (1.0f / 20.0f);
    float v = 0.f;
    #pragma unroll
    for (int e = 0; e < 20; ++e) { float d = ss[t + e] - mn; v += d * d; }
    thrw[t] = mn + GAMMA_C * sqrtf(v * (1.0f / 19.0f));   // ddof=1
  }
  __syncthreads();
  float th = (t <= 18) ? thrw[0] : thrw[t - 19];
  bnd[b * 256 + t] = (ss[t] > th) ? 1 : 0;
}

// ---------------- 5) sims = q qT per batch ----------------
__global__ __launch_bounds__(256) void k_sims(const float* __restrict__ q,
                                              float* __restrict__ sims) {
  __shared__ float Qs[32 * 68];
  __shared__ float Ws[32 * 68];
  int b = blockIdx.z;
  int m0 = blockIdx.y * 64, n0 = blockIdx.x * 64;
  float acc[4][4] = {};
  const float* qb = q + (size_t)b * Ss * Dd;
  gemm64x64_k512(qb + (size_t)m0 * 512, qb + (size_t)n0 * 512, acc, Qs, Ws);
  int t = threadIdx.x, tn = t & 15, tm = t >> 4;
  float* outp = sims + (size_t)b * Ss * Ss;
  #pragma unroll
  for (int i = 0; i < 4; ++i) {
    float4 v = make_float4(acc[i][0], acc[i][1], acc[i][2], acc[i][3]);
    *(float4*)&outp[(size_t)(m0 + tm * 4 + i) * 256 + n0 + tn * 4] = v;
  }
}

// ---------------- 6) per-row prefix sums R[i][0..256] and deg ----------------
__global__ __launch_bounds__(256) void k_rowpref(const float* __restrict__ sims,
                                                 float* __restrict__ R,
                                                 float* __restrict__ deg) {
  int wid = blockIdx.x * 4 + (threadIdx.x >> 6);   // 0..511 (b*256+i)
  int lane = threadIdx.x & 63;
  int b = wid >> 8, i = wid & 255;
  const float* row = sims + (size_t)b * 65536 + (size_t)i * 256;
  float4 v = *(const float4*)&row[lane * 4];
  float c0 = v.x, c1 = c0 + v.y, c2 = c1 + v.z, c3 = c2 + v.w;
  float ls = c3;
  float sc = ls;
  for (int off = 1; off < 64; off <<= 1) {
    float u = __shfl_up(sc, off);
    if (lane >= off) sc += u;
  }
  float ex = sc - ls;
  float* Rr = R + (size_t)b * (256 * 257) + (size_t)i * 257;
  Rr[lane * 4 + 1] = ex + c0;
  Rr[lane * 4 + 2] = ex + c1;
  Rr[lane * 4 + 3] = ex + c2;
  Rr[lane * 4 + 4] = ex + c3;
  if (lane == 0) Rr[0] = 0.f;
  if (lane == 63) deg[b * 256 + i] = ex + c3;
}

// ---------------- 7) segment aggregates + O(1) candidate eval + rebuild ----------------
__global__ __launch_bounds__(256) void k_refine(const int* __restrict__ bnd,
                                                const float* __restrict__ R,
                                                const float* __restrict__ deg,
                                                int* __restrict__ nseg,
                                                int* __restrict__ segstart_o,
                                                int* __restrict__ segcnt_o) {
  __shared__ int sb[256], lab[256];
  __shared__ int segst[258];
  __shared__ float Dc[257], Sc[257], Cr[257];
  __shared__ float sh[6];   // tot tote Qun Csum curQ curC
  int b = blockIdx.x, t = threadIdx.x;
  sb[t] = bnd[b * 256 + t];
  for (int c = t; c < 258; c += 256) segst[c] = -1;
  __syncthreads();
  int a = 0;
  for (int i = 0; i <= t; ++i) a += sb[i];
  lab[t] = a;
  __syncthreads();
  if (t == 0 || lab[t - 1] != lab[t]) segst[lab[t]] = t;
  __syncthreads();
  int nb = lab[255];
  const float* Rb = R + (size_t)b * (256 * 257);
  const float* db = deg + b * 256;
  for (int c = t; c <= nb; c += 256) {
    float Dv = 0.f, Sv = 0.f, Cv = 0.f;
    int a1 = segst[c];
    if (a1 >= 0) {
      int e1 = (c == nb) ? 255 : (segst[c + 1] - 1);
      for (int i = a1; i <= e1; ++i) Dv += db[i];
      for (int i = a1; i <= e1; ++i) Sv += Rb[i * 257 + e1 + 1] - Rb[i * 257 + a1];
      if (c < nb) {
        int a2 = segst[c + 1];
        int e2 = (c + 1 == nb) ? 255 : (segst[c + 2] - 1);
        for (int i = a1; i < a2; ++i) Cv += Rb[i * 257 + e2 + 1] - Rb[i * 257 + a2];
      }
    }
    Dc[c] = Dv; Sc[c] = Sv; Cr[c] = Cv;
  }
  __syncthreads();
  if (t == 0) {
    float tot = 0.f;
    for (int i = 0; i < 256; ++i) tot += db[i];
    float tote = tot + 1e-10f;
    float Qun = 0.f, Cs = 0.f;
    for (int c = 0; c <= nb; ++c) {
      Qun += Sc[c] - Dc[c] * Dc[c] / tote;
      Cs  += (Dc[c] - Sc[c]) / (fminf(Dc[c], tot - Dc[c]) + 1e-10f);
    }
    sh[0] = tot; sh[1] = tote; sh[2] = Qun; sh[3] = Cs;
    sh[4] = Qun / tote; sh[5] = Cs / (float)(nb + 1);
  }
  __syncthreads();
  int r = sb[t];
  if (r == 1) {
    float tot = sh[0], tote = sh[1], Qun = sh[2], Cs = sh[3], curQ = sh[4], curC = sh[5];
    int c2 = lab[t], c1 = c2 - 1;
    if (segst[c1] < 0) {
      // merging with empty label-0: Q bitwise-identical; C-sum identical, count drops by 1
      float newC0 = Cs / (float)nb;
      if (newC0 < curC) r = 0;
    } else {
      float D1 = Dc[c1], S1 = Sc[c1], D2 = Dc[c2], S2 = Sc[c2];
      float Dm = D1 + D2, Sm = S1 + S2 + 2.0f * Cr[c1];
      float tq1 = S1 - D1 * D1 / tote;
      float tq2 = S2 - D2 * D2 / tote;
      float tqm = Sm - Dm * Dm / tote;
      float newQ = (Qun - tq1 - tq2 + tqm) / tote;
      float tc1 = (D1 - S1) / (fminf(D1, tot - D1) + 1e-10f);
      float tc2 = (D2 - S2) / (fminf(D2, tot - D2) + 1e-10f);
      float tcm = (Dm - Sm) / (fminf(Dm, tot - Dm) + 1e-10f);
      float newC = (Cs - tc1 - tc2 + tcm) / (float)nb;
      if (newQ > curQ || newC < curC) r = 0;
    }
  }
  __syncthreads();
  sb[t] = r;
  __syncthreads();
  if (t == 0) {
    int ns = 0, st = 0;
    for (int i = 1; i <= 256; ++i) {
      if (i == 256 || sb[i] == 1) {
        segstart_o[b * 257 + ns] = st;
        segcnt_o[b * 257 + ns] = i - st;
        ns++;
        st = i;
      }
    }
    nseg[b] = ns;
  }
}

// ---------------- 8) slot assignment + continuity top-k ----------------
__global__ __launch_bounds__(256) void k_slots(const int* __restrict__ nseg,
                                               const int* __restrict__ segstart_i,
                                               const int* __restrict__ segcnt_i,
                                               const int* __restrict__ meml_in,
                                               int* __restrict__ slot_b,
                                               int* __restrict__ slot_start,
                                               int* __restrict__ slot_cnt,
                                               int* __restrict__ cont) {
  int t = threadIdx.x;
  slot_cnt[t] = 0; slot_b[t] = 0; slot_start[t] = 0;
  __syncthreads();
  if (t == 0) {
    int rank = 0;
    for (int b = 0; b < 2; ++b) {
      int ns = nseg[b];
      for (int s = 0; s < ns; ++s) {
        int sl = rank & 255;  // rank % NUM_MEM, later writes win (matches flat order)
        slot_b[sl] = b;
        slot_start[sl] = segstart_i[b * 257 + s];
        slot_cnt[sl] = segcnt_i[b * 257 + s];
        rank++;
      }
    }
    // recency top-4: largest valid indices desc, then invalid asc (stable ties at -1)
    int k = 0;
    for (int n = 255; n >= 0 && k < 4; --n)
      if (slot_cnt[n] > 0 || meml_in[n] > 0) cont[k++] = n;
    for (int n = 0; n < 256 && k < 4; ++n)
      if (!(slot_cnt[n] > 0 || meml_in[n] > 0)) cont[k++] = n;
  }
}

// ---------------- 9) qbar, qm ----------------
__global__ __launch_bounds__(256) void k_qbar(const float* __restrict__ q,
                                              float* __restrict__ qbar) {
  int id = blockIdx.x * 256 + threadIdx.x;   // <1024
  int b = id >> 9, d = id & 511;
  float s = 0.f;
  for (int ss2 = 0; ss2 < 256; ++ss2) s += q[((size_t)(b * 256 + ss2)) * 512 + d];
  qbar[id] = s * (1.0f / 256.0f);
}

__global__ __launch_bounds__(256) void k_qm(const float* __restrict__ qbar,
                                            const float* __restrict__ simw,
                                            const float* __restrict__ simb,
                                            float* __restrict__ qm) {
  int wid = blockIdx.x * 4 + (threadIdx.x >> 6);  // <1024
  int lane = threadIdx.x & 63;
  int b = wid >> 9, e = wid & 511;
  float a = 0.f;
  #pragma unroll
  for (int j = 0; j < 8; ++j)
    a += qbar[b * 512 + lane + 64 * j] * simw[(size_t)e * 512 + lane + 64 * j];
  #pragma unroll
  for (int off = 32; off; off >>= 1) a += __shfl_xor(a, off);
  if (lane == 0) qm[b * 512 + e] = a + simb[e];
}

// ---------------- 10) scores ----------------
__global__ __launch_bounds__(256) void k_scores(const float* __restrict__ q,
                                                const float* __restrict__ memk,
                                                const int* __restrict__ meml,
                                                const int* __restrict__ slot_b,
                                                const int* __restrict__ slot_start,
                                                const int* __restrict__ slot_cnt,
                                                const float* __restrict__ qm,
                                                float* __restrict__ scores) {
  int wid = blockIdx.x * 4 + (threadIdx.x >> 6);  // 0..511
  int lane = threadIdx.x & 63;
  int b = wid >> 8, n = wid & 255;
  const float* kp = nullptr;
  if (slot_cnt[n] > 0) kp = q + ((size_t)(slot_b[n] * 256 + slot_start[n])) * 512;
  else if (meml[n] > 0) kp = memk + (size_t)n * 512;
  float a = 0.f;
  if (kp) {
    #pragma unroll
    for (int j = 0; j < 8; ++j) a += qm[b * 512 + lane + 64 * j] * kp[lane + 64 * j];
    #pragma unroll
    for (int off = 32; off; off >>= 1) a += __shfl_xor(a, off);
  }
  if (lane == 0) scores[b * 256 + n] = kp ? a : -1000000000.0f;
}

// ---------------- 11) stable top-8 ----------------
__global__ __launch_bounds__(256) void k_topk(const float* __restrict__ scores,
                                              int* __restrict__ topi) {
  __shared__ unsigned char ch[2][256];
  int t = threadIdx.x;
  ch[0][t] = 0; ch[1][t] = 0;
  __syncthreads();
  if (t < 2) {
    for (int k = 0; k < 8; ++k) {
      float best = -3.4e38f; int bi = 0;
      for (int n = 0; n < 256; ++n)
        if (!ch[t][n]) { float s = scores[t * 256 + n]; if (s > best) { best = s; bi = n; } }
      ch[t][bi] = 1;
      topi[t * 8 + k] = bi;
    }
  }
}

// ---------------- 12) gather memory rows -> xg ----------------
__global__ __launch_bounds__(256) void k_gather(const float* __restrict__ q,
                                                const float* __restrict__ memv,
                                                const int* __restrict__ topi,
                                                const int* __restrict__ cont,
                                                const int* __restrict__ slot_b,
                                                const int* __restrict__ slot_start,
                                                const int* __restrict__ slot_cnt,
                                                float* __restrict__ xg) {
  int id = blockIdx.x * 256 + threadIdx.x;   // < 196608
  int d = id & 511;
  int rb = id >> 9;          // 0..383
  int b = rb / 192;
  int r = rb - b * 192;
  int p = r & 15;
  int slot = (r < 128) ? topi[b * 8 + (r >> 4)] : cont[(r - 128) >> 4];
  float val;
  int cnt = slot_cnt[slot];
  if (cnt > 0) {
    int ml = cnt < 16 ? cnt : 16;
    val = (p < ml) ? q[((size_t)(slot_b[slot] * 256 + slot_start[slot] + p)) * 512 + d] : 0.f;
  } else {
    val = memv[((size_t)slot * 16 + p) * 512 + d];
  }
  xg[id] = val;
}

// ---------------- 13) storage MLP ----------------
__global__ __launch_bounds__(256) void k_mlp1(const float* __restrict__ xg,
                                              const float* __restrict__ w1,
                                              const float* __restrict__ b1,
                                              float* __restrict__ h) {
  __shared__ float Qs[32 * 68];
  __shared__ float Ws[32 * 68];
  int n0 = blockIdx.x * 64, m0 = blockIdx.y * 64;
  float acc[4][4] = {};
  gemm64x64_k512(xg + (size_t)m0 * 512, w1 + (size_t)n0 * 512, acc, Qs, Ws);
  int t = threadIdx.x, tn = t & 15, tm = t >> 4;
  #pragma unroll
  for (int i = 0; i < 4; ++i) {
    int m = m0 + tm * 4 + i;
    #pragma unroll
    for (int j = 0; j < 4; ++j) {
      int n = n0 + tn * 4 + j;
      h[(size_t)m * 512 + n] = fmaxf(acc[i][j] + b1[n], 0.f);
    }
  }
}

__global__ __launch_bounds__(256) void k_mlp2(const float* __restrict__ h,
                                              const float* __restrict__ w2,
                                              const float* __restrict__ b2,
                                              float* __restrict__ out) {
  __shared__ float Qs[32 * 68];
  __shared__ float Ws[32 * 68];
  int n0 = blockIdx.x * 64, m0 = blockIdx.y * 64;
  float acc[4][4] = {};
  gemm64x64_k512(h + (size_t)m0 * 512, w2 + (size_t)n0 * 512, acc, Qs, Ws);
  int t = threadIdx.x, tn = t & 15, tm = t >> 4;
  #pragma unroll
  for (int i = 0; i < 4; ++i) {
    int m = m0 + tm * 4 + i;
    int b = (m >= 192) ? 1 : 0;
    int rr = m - b * 192;
    int n = n0 + tn * 4;
    float4 v = make_float4(acc[i][0] + b2[n], acc[i][1] + b2[n + 1],
                           acc[i][2] + b2[n + 2], acc[i][3] + b2[n + 3]);
    size_t base = OC1 + ((size_t)(b * 448 + rr)) * 512 + n;
    *(float4*)&out[base] = v;
    *(float4*)&out[base + NCTX] = v;
  }
}

// ---------------- 14) passthrough copies + mask ----------------
__global__ __launch_bounds__(256) void k_copy(const float* __restrict__ q,
                                              const float* __restrict__ key,
                                              const float* __restrict__ amask,
                                              float* __restrict__ out) {
  int id = blockIdx.x * 256 + threadIdx.x;
  if (id < 262144) { out[id] = q[id]; return; }
  if (id < 524288) {
    int id2 = id - 262144;
    int b = id2 >> 17;
    int s = (id2 >> 9) & 255;
    int d = id2 & 511;
    float v = key[id2];
    size_t p = OC1 + ((size_t)(b * 448 + 192 + s)) * 512 + d;
    out[p] = v;
    out[p + NCTX] = v;
    return;
  }
  if (id < 525184) {
    int j = id - 524288;   // 0..895
    int b = j / 448, c = j - b * 448;
    out[OMASK + j] = (c < 192) ? 1.0f : amask[b * 256 + (c - 192)];
  }
}

// ---------------- launch ----------------
extern "C" void kernel_launch(void* const* d_in, const int* in_sizes, int n_in,
                              void* d_out, int out_size, void* d_ws, size_t ws_size,
                              hipStream_t stream) {
  // Hard guard: if workspace is smaller than required, skip (harness will
  // report a clean mismatch instead of OOB-crashing the container).
  if (ws_size < WS_FLOATS_NEEDED * sizeof(float)) return;

  const float* q     = (const float*)d_in[0];
  const float* key   = (const float*)d_in[1];
  const float* amask = (const float*)d_in[3];
  const int*   tgt   = (const int*)d_in[4];
  const float* bw    = (const float*)d_in[5];
  const float* w1    = (const float*)d_in[6];
  const float* b1    = (const float*)d_in[7];
  const float* w2    = (const float*)d_in[8];
  const float* b2    = (const float*)d_in[9];
  const float* simw  = (const float*)d_in[10];
  const float* simb  = (const float*)d_in[11];
  const float* memk  = (const float*)d_in[12];
  const float* memv  = (const float*)d_in[13];
  const int*   meml  = (const int*)d_in[14];
  float* out = (float*)d_out;

  float* w = (float*)d_ws;
  float* p_partial = w;                      // 500*512 = 256000
  float* p_lse    = p_partial + 256000;      // 512
  float* p_sur    = p_lse + 512;             // 512
  float* p_sims   = p_sur + 512;             // 2*256*256 = 131072
  float* p_R      = p_sims + 131072;         // 2*256*257 = 131584
  float* p_deg    = p_R + 131584;            // 512
  float* p_qbar   = p_deg + 512;             // 1024
  float* p_qm     = p_qbar + 1024;           // 1024
  float* p_scores = p_qm + 1024;             // 512
  float* p_xg     = p_scores + 512;          // 2*192*512 = 196608
  float* p_h      = p_xg + 196608;           // 196608
  int* ip         = (int*)(p_h + 196608);
  int* ip_bnd     = ip;                      // 512
  int* ip_nseg    = ip + 512;                // 2
  int* ip_segst   = ip + 514;                // 514
  int* ip_segcnt  = ip + 1028;               // 514
  int* ip_slotb   = ip + 1542;               // 256
  int* ip_slotst  = ip + 1798;               // 256
  int* ip_slotcnt = ip + 2054;               // 256
  int* ip_topi    = ip + 2310;               // 16
  int* ip_cont    = ip + 2326;               // 4

  k_logits<<<dim3(500, 8), 256, 0, stream>>>(q, bw, p_partial);
  k_lse<<<2, 256, 0, stream>>>(p_partial, p_lse);
  k_zt<<<128, 256, 0, stream>>>(q, bw, tgt, p_lse, p_sur);
  k_bound<<<2, 256, 0, stream>>>(p_sur, ip_bnd);
  k_sims<<<dim3(4, 4, 2), 256, 0, stream>>>(q, p_sims);
  k_rowpref<<<128, 256, 0, stream>>>(p_sims, p_R, p_deg);
  k_refine<<<2, 256, 0, stream>>>(ip_bnd, p_R, p_deg, ip_nseg, ip_segst, ip_segcnt);
  k_slots<<<1, 256, 0, stream>>>(ip_nseg, ip_segst, ip_segcnt, meml,
                                 ip_slotb, ip_slotst, ip_slotcnt, ip_cont);
  k_qbar<<<4, 256, 0, stream>>>(q, p_qbar);
  k_qm<<<256, 256, 0, stream>>>(p_qbar, simw, simb, p_qm);
  k_scores<<<128, 256, 0, stream>>>(q, memk, meml, ip_slotb, ip_slotst, ip_slotcnt,
                                    p_qm, p_scores);
  k_topk<<<1, 256, 0, stream>>>(p_scores, ip_topi);
  k_gather<<<768, 256, 0, stream>>>(q, memv, ip_topi, ip_cont,
                                    ip_slotb, ip_slotst, ip_slotcnt, p_xg);
  k_mlp1<<<dim3(8, 6), 256, 0, stream>>>(p_xg, w1, b1, p_h);
  k_mlp2<<<dim3(8, 6), 256, 0, stream>>>(p_h, w2, b2, out);
  k_copy<<<2052, 256, 0, stream>>>(q, key, amask, out);
}

// Round 7
// 594.061 us; speedup vs baseline: 1.3366x; 1.3366x over previous
//
#include <hip/hip_runtime.h>

// ---------------- problem constants ----------------
constexpr int Bb = 2;
constexpr int Ss = 256;
constexpr int Dd = 512;
constexpr int Vv = 32000;
constexpr int NVB = Vv / 64;          // 500 v-bands
constexpr float GAMMA_C = 2.0f;
constexpr int MEMLEN = 16;
constexpr int NMEM = 256;
constexpr int MTOT = (8 + 4) * MEMLEN;   // 192
constexpr int CTXROWS = MTOT + Ss;       // 448

// output layout (floats)
constexpr size_t NQ   = (size_t)Bb * Ss * Dd;        // 262144
constexpr size_t OC1  = NQ;                          // 262144
constexpr size_t NCTX = (size_t)Bb * CTXROWS * Dd;   // 458752
constexpr size_t OC2  = OC1 + NCTX;                  // 720896
constexpr size_t OMASK = OC2 + NCTX;                 // 1179648

// workspace layout (floats); total ≈ 3.67 MB
constexpr size_t WS_FLOATS_NEEDED = 256000 + 512 + 512 + 131072 + 131584 + 512 +
                                    1024 + 1024 + 512 + 196608 + 196608 + 4096;

// ---------------- shared 64x64 fp32 GEMM core (K=512, lda=ldb=512) ----------------
// acc[i][j] = sum_k A[tm*4+i][k] * B[tn*4+j][k]   (A,B row-major, 512 cols)
// LDS layout: float4-unit addr4(k, m4) = k*16 + (m4 ^ ((k>>2)&7))   [XOR swizzle]
//  - transpose-write: 8 distinct (k>>2) per wave spread banks -> 2-way (free)
//  - A/B fragment reads: <=2-way. FMA accumulation order UNCHANGED (bit-exact).
__device__ __forceinline__ void gemm64x64_k512(const float* __restrict__ A,
                                               const float* __restrict__ Bm,
                                               float acc[4][4],
                                               float4* __restrict__ Qs4,
                                               float4* __restrict__ Ws4) {
  const int t = threadIdx.x;
  const int tn = t & 15, tm = t >> 4;
  float* __restrict__ Qf = (float*)Qs4;
  float* __restrict__ Wf = (float*)Ws4;
  #pragma unroll 2
  for (int kc = 0; kc < 512; kc += 32) {
    #pragma unroll
    for (int e = 0; e < 2; ++e) {
      const int idx4 = t + 256 * e;        // 0..511
      const int m = idx4 >> 3;             // 0..63
      const int kg = idx4 & 7;             // k-group, k4 = kg*4
      const float4 qa = *(const float4*)(A + (size_t)m * 512 + kc + kg * 4);
      const float4 wb = *(const float4*)(Bm + (size_t)m * 512 + kc + kg * 4);
      // element (k = kg*4 + j, m) -> float index ((kg*4+j)*16 + ((m>>2)^kg))*4 + (m&3)
      const int fb = ((kg * 4) * 16 + ((m >> 2) ^ kg)) * 4 + (m & 3);
      Qf[fb]       = qa.x;
      Qf[fb + 64]  = qa.y;
      Qf[fb + 128] = qa.z;
      Qf[fb + 192] = qa.w;
      Wf[fb]       = wb.x;
      Wf[fb + 64]  = wb.y;
      Wf[fb + 128] = wb.z;
      Wf[fb + 192] = wb.w;
    }
    __syncthreads();
    #pragma unroll
    for (int k = 0; k < 32; ++k) {
      const int swz = (k >> 2) & 7;
      const float4 a4 = Qs4[k * 16 + (tm ^ swz)];
      const float4 b4 = Ws4[k * 16 + (tn ^ swz)];
      const float av[4] = {a4.x, a4.y, a4.z, a4.w};
      const float bv[4] = {b4.x, b4.y, b4.z, b4.w};
      #pragma unroll
      for (int i = 0; i < 4; ++i)
        #pragma unroll
        for (int j = 0; j < 4; ++j)
          acc[i][j] += av[i] * bv[j];
    }
    __syncthreads();
  }
}

// ---------------- 1) logits tile + per-row band sum(exp(z)) ----------------
__global__ __launch_bounds__(256) void k_logits(const float* __restrict__ q,
                                                const float* __restrict__ bw,
                                                float* __restrict__ partial) {
  __shared__ float4 Qs4[512];
  __shared__ float4 Ws4[512];
  __shared__ float red[64 * 17];
  const int bv = blockIdx.x;   // 0..499
  const int bm = blockIdx.y;   // 0..7
  float acc[4][4] = {};
  gemm64x64_k512(q + (size_t)bm * 64 * 512, bw + (size_t)bv * 64 * 512, acc, Qs4, Ws4);
  const int t = threadIdx.x, tn = t & 15, tm = t >> 4;
  #pragma unroll
  for (int i = 0; i < 4; ++i) {
    float s = 0.f;
    #pragma unroll
    for (int j = 0; j < 4; ++j) s += expf(acc[i][j]);
    red[(tm * 4 + i) * 17 + tn] = s;
  }
  __syncthreads();
  if (t < 64) {
    float s = 0.f;
    #pragma unroll
    for (int j = 0; j < 16; ++j) s += red[t * 17 + j];
    partial[(size_t)bv * 512 + bm * 64 + t] = s;   // [band][row] for coalesced combine
  }
}

// ---------------- 2) combine partials -> lse ----------------
__global__ __launch_bounds__(256) void k_lse(const float* __restrict__ partial,
                                             float* __restrict__ lse) {
  int r = blockIdx.x * 256 + threadIdx.x;   // 0..511
  double s = 0.0;
  for (int j = 0; j < NVB; ++j) s += (double)partial[(size_t)j * 512 + r];
  lse[r] = (float)log(s);
}

// ---------------- 3) z_target, surprise = lse - z_target ----------------
__global__ __launch_bounds__(256) void k_zt(const float* __restrict__ q,
                                            const float* __restrict__ bw,
                                            const int* __restrict__ tgt,
                                            const float* __restrict__ lse,
                                            float* __restrict__ sur) {
  int wid = blockIdx.x * 4 + (threadIdx.x >> 6);  // 0..511
  int lane = threadIdx.x & 63;
  int tg = tgt[wid];
  const float* qp = q + (size_t)wid * 512;
  const float* wp = bw + (size_t)tg * 512;
  float a = 0.f;
  #pragma unroll
  for (int j = 0; j < 8; ++j) a += qp[lane + 64 * j] * wp[lane + 64 * j];
  #pragma unroll
  for (int off = 32; off; off >>= 1) a += __shfl_xor(a, off);
  if (lane == 0) sur[wid] = lse[wid] - a;
}

// ---------------- 4) windowed threshold -> boundaries ----------------
__global__ __launch_bounds__(256) void k_bound(const float* __restrict__ sur,
                                               int* __restrict__ bnd) {
  __shared__ float ss[256];
  __shared__ float thrw[237];
  int b = blockIdx.x, t = threadIdx.x;
  ss[t] = sur[b * 256 + t];
  __syncthreads();
  if (t < 237) {
    float mn = 0.f;
    #pragma unroll
    for (int e = 0; e < 20; ++e) mn += ss[t + e];
    mn *= (1.0f / 20.0f);
    float v = 0.f;
    #pragma unroll
    for (int e = 0; e < 20; ++e) { float d = ss[t + e] - mn; v += d * d; }
    thrw[t] = mn + GAMMA_C * sqrtf(v * (1.0f / 19.0f));   // ddof=1
  }
  __syncthreads();
  float th = (t <= 18) ? thrw[0] : thrw[t - 19];
  bnd[b * 256 + t] = (ss[t] > th) ? 1 : 0;
}

// ---------------- 5) sims = q qT per batch ----------------
__global__ __launch_bounds__(256) void k_sims(const float* __restrict__ q,
                                              float* __restrict__ sims) {
  __shared__ float4 Qs4[512];
  __shared__ float4 Ws4[512];
  int b = blockIdx.z;
  int m0 = blockIdx.y * 64, n0 = blockIdx.x * 64;
  float acc[4][4] = {};
  const float* qb = q + (size_t)b * Ss * Dd;
  gemm64x64_k512(qb + (size_t)m0 * 512, qb + (size_t)n0 * 512, acc, Qs4, Ws4);
  int t = threadIdx.x, tn = t & 15, tm = t >> 4;
  float* outp = sims + (size_t)b * Ss * Ss;
  #pragma unroll
  for (int i = 0; i < 4; ++i) {
    float4 v = make_float4(acc[i][0], acc[i][1], acc[i][2], acc[i][3]);
    *(float4*)&outp[(size_t)(m0 + tm * 4 + i) * 256 + n0 + tn * 4] = v;
  }
}

// ---------------- 6) per-row prefix sums R[i][0..256] and deg ----------------
__global__ __launch_bounds__(256) void k_rowpref(const float* __restrict__ sims,
                                                 float* __restrict__ R,
                                                 float* __restrict__ deg) {
  int wid = blockIdx.x * 4 + (threadIdx.x >> 6);   // 0..511 (b*256+i)
  int lane = threadIdx.x & 63;
  int b = wid >> 8, i = wid & 255;
  const float* row = sims + (size_t)b * 65536 + (size_t)i * 256;
  float4 v = *(const float4*)&row[lane * 4];
  float c0 = v.x, c1 = c0 + v.y, c2 = c1 + v.z, c3 = c2 + v.w;
  float ls = c3;
  float sc = ls;
  for (int off = 1; off < 64; off <<= 1) {
    float u = __shfl_up(sc, off);
    if (lane >= off) sc += u;
  }
  float ex = sc - ls;
  float* Rr = R + (size_t)b * (256 * 257) + (size_t)i * 257;
  Rr[lane * 4 + 1] = ex + c0;
  Rr[lane * 4 + 2] = ex + c1;
  Rr[lane * 4 + 3] = ex + c2;
  Rr[lane * 4 + 4] = ex + c3;
  if (lane == 0) Rr[0] = 0.f;
  if (lane == 63) deg[b * 256 + i] = ex + c3;
}

// ---------------- 7) segment aggregates + O(1) candidate eval + rebuild ----------------
__global__ __launch_bounds__(256) void k_refine(const int* __restrict__ bnd,
                                                const float* __restrict__ R,
                                                const float* __restrict__ deg,
                                                int* __restrict__ nseg,
                                                int* __restrict__ segstart_o,
                                                int* __restrict__ segcnt_o) {
  __shared__ int sb[256], lab[256];
  __shared__ int segst[258];
  __shared__ float Dc[257], Sc[257], Cr[257];
  __shared__ float degsh[256];
  __shared__ float sh[6];   // tot tote Qun Csum curQ curC
  int b = blockIdx.x, t = threadIdx.x;
  sb[t] = bnd[b * 256 + t];
  degsh[t] = deg[b * 256 + t];       // stage deg -> LDS (values identical; order of sums unchanged)
  for (int c = t; c < 258; c += 256) segst[c] = -1;
  __syncthreads();
  int a = 0;
  for (int i = 0; i <= t; ++i) a += sb[i];
  lab[t] = a;
  __syncthreads();
  if (t == 0 || lab[t - 1] != lab[t]) segst[lab[t]] = t;
  __syncthreads();
  int nb = lab[255];
  const float* Rb = R + (size_t)b * (256 * 257);
  for (int c = t; c <= nb; c += 256) {
    float Dv = 0.f, Sv = 0.f, Cv = 0.f;
    int a1 = segst[c];
    if (a1 >= 0) {
      int e1 = (c == nb) ? 255 : (segst[c + 1] - 1);
      for (int i = a1; i <= e1; ++i) Dv += degsh[i];
      for (int i = a1; i <= e1; ++i) Sv += Rb[i * 257 + e1 + 1] - Rb[i * 257 + a1];
      if (c < nb) {
        int a2 = segst[c + 1];
        int e2 = (c + 1 == nb) ? 255 : (segst[c + 2] - 1);
        for (int i = a1; i < a2; ++i) Cv += Rb[i * 257 + e2 + 1] - Rb[i * 257 + a2];
      }
    }
    Dc[c] = Dv; Sc[c] = Sv; Cr[c] = Cv;
  }
  __syncthreads();
  if (t == 0) {
    float tot = 0.f;
    for (int i = 0; i < 256; ++i) tot += degsh[i];
    float tote = tot + 1e-10f;
    float Qun = 0.f, Cs = 0.f;
    for (int c = 0; c <= nb; ++c) {
      Qun += Sc[c] - Dc[c] * Dc[c] / tote;
      Cs  += (Dc[c] - Sc[c]) / (fminf(Dc[c], tot - Dc[c]) + 1e-10f);
    }
    sh[0] = tot; sh[1] = tote; sh[2] = Qun; sh[3] = Cs;
    sh[4] = Qun / tote; sh[5] = Cs / (float)(nb + 1);
  }
  __syncthreads();
  int r = sb[t];
  if (r == 1) {
    float tot = sh[0], tote = sh[1], Qun = sh[2], Cs = sh[3], curQ = sh[4], curC = sh[5];
    int c2 = lab[t], c1 = c2 - 1;
    if (segst[c1] < 0) {
      // merging with empty label-0: Q bitwise-identical; C-sum identical, count drops by 1
      float newC0 = Cs / (float)nb;
      if (newC0 < curC) r = 0;
    } else {
      float D1 = Dc[c1], S1 = Sc[c1], D2 = Dc[c2], S2 = Sc[c2];
      float Dm = D1 + D2, Sm = S1 + S2 + 2.0f * Cr[c1];
      float tq1 = S1 - D1 * D1 / tote;
      float tq2 = S2 - D2 * D2 / tote;
      float tqm = Sm - Dm * Dm / tote;
      float newQ = (Qun - tq1 - tq2 + tqm) / tote;
      float tc1 = (D1 - S1) / (fminf(D1, tot - D1) + 1e-10f);
      float tc2 = (D2 - S2) / (fminf(D2, tot - D2) + 1e-10f);
      float tcm = (Dm - Sm) / (fminf(Dm, tot - Dm) + 1e-10f);
      float newC = (Cs - tc1 - tc2 + tcm) / (float)nb;
      if (newQ > curQ || newC < curC) r = 0;
    }
  }
  __syncthreads();
  sb[t] = r;
  __syncthreads();
  if (t == 0) {
    int ns = 0, st = 0;
    for (int i = 1; i <= 256; ++i) {
      if (i == 256 || sb[i] == 1) {
        segstart_o[b * 257 + ns] = st;
        segcnt_o[b * 257 + ns] = i - st;
        ns++;
        st = i;
      }
    }
    nseg[b] = ns;
  }
}

// ---------------- 8) slot assignment + continuity top-k (PARALLEL, exact semantics) ----
// Serial ref: rank 0..total-1 written in order, slot = rank % 256, later writes win
// -> slot sl holds the LARGEST rank ≡ sl (mod 256) below total. O(1) per thread.
__global__ __launch_bounds__(256) void k_slots(const int* __restrict__ nseg,
                                               const int* __restrict__ segstart_i,
                                               const int* __restrict__ segcnt_i,
                                               const int* __restrict__ meml_in,
                                               int* __restrict__ slot_b,
                                               int* __restrict__ slot_start,
                                               int* __restrict__ slot_cnt,
                                               int* __restrict__ cont) {
  __shared__ unsigned char validsh[256];
  __shared__ int ns01[2];
  int t = threadIdx.x;
  if (t < 2) ns01[t] = nseg[t];
  __syncthreads();
  int ns0 = ns01[0], total = ns0 + ns01[1];
  int rank = -1;
  for (int r = t; r < total; r += 256) rank = r;  // largest rank ≡ t (mod 256), < total
  int bb = 0, st = 0, ct = 0;
  if (rank >= 0) {
    bb = (rank >= ns0) ? 1 : 0;
    int s = rank - bb * ns0;
    st = segstart_i[bb * 257 + s];
    ct = segcnt_i[bb * 257 + s];
  }
  slot_b[t] = bb; slot_start[t] = st; slot_cnt[t] = ct;
  validsh[t] = (ct > 0 || meml_in[t] > 0) ? 1 : 0;
  __syncthreads();
  if (t == 0) {
    // recency top-4: largest valid indices desc, then invalid asc (matches serial)
    int k = 0;
    for (int n = 255; n >= 0 && k < 4; --n) if (validsh[n]) cont[k++] = n;
    for (int n = 0; n < 256 && k < 4; ++n) if (!validsh[n]) cont[k++] = n;
  }
}

// ---------------- 9) qbar, qm ----------------
__global__ __launch_bounds__(256) void k_qbar(const float* __restrict__ q,
                                              float* __restrict__ qbar) {
  int id = blockIdx.x * 256 + threadIdx.x;   // <1024
  int b = id >> 9, d = id & 511;
  float s = 0.f;
  for (int ss2 = 0; ss2 < 256; ++ss2) s += q[((size_t)(b * 256 + ss2)) * 512 + d];
  qbar[id] = s * (1.0f / 256.0f);
}

__global__ __launch_bounds__(256) void k_qm(const float* __restrict__ qbar,
                                            const float* __restrict__ simw,
                                            const float* __restrict__ simb,
                                            float* __restrict__ qm) {
  int wid = blockIdx.x * 4 + (threadIdx.x >> 6);  // <1024
  int lane = threadIdx.x & 63;
  int b = wid >> 9, e = wid & 511;
  float a = 0.f;
  #pragma unroll
  for (int j = 0; j < 8; ++j)
    a += qbar[b * 512 + lane + 64 * j] * simw[(size_t)e * 512 + lane + 64 * j];
  #pragma unroll
  for (int off = 32; off; off >>= 1) a += __shfl_xor(a, off);
  if (lane == 0) qm[b * 512 + e] = a + simb[e];
}

// ---------------- 10) scores ----------------
__global__ __launch_bounds__(256) void k_scores(const float* __restrict__ q,
                                                const float* __restrict__ memk,
                                                const int* __restrict__ meml,
                                                const int* __restrict__ slot_b,
                                                const int* __restrict__ slot_start,
                                                const int* __restrict__ slot_cnt,
                                                const float* __restrict__ qm,
                                                float* __restrict__ scores) {
  int wid = blockIdx.x * 4 + (threadIdx.x >> 6);  // 0..511
  int lane = threadIdx.x & 63;
  int b = wid >> 8, n = wid & 255;
  const float* kp = nullptr;
  if (slot_cnt[n] > 0) kp = q + ((size_t)(slot_b[n] * 256 + slot_start[n])) * 512;
  else if (meml[n] > 0) kp = memk + (size_t)n * 512;
  float a = 0.f;
  if (kp) {
    #pragma unroll
    for (int j = 0; j < 8; ++j) a += qm[b * 512 + lane + 64 * j] * kp[lane + 64 * j];
    #pragma unroll
    for (int off = 32; off; off >>= 1) a += __shfl_xor(a, off);
  }
  if (lane == 0) scores[b * 256 + n] = kp ? a : -1000000000.0f;
}

// ---------------- 11) stable top-8 (PARALLEL, exact tie-semantics) ----------------
// Serial ref: argmax scan n=0..255 with strict '>' => max value, lowest index on ties.
__global__ __launch_bounds__(64) void k_topk(const float* __restrict__ scores,
                                             int* __restrict__ topi) {
  int b = blockIdx.x, lane = threadIdx.x;
  float v[4];
  #pragma unroll
  for (int j = 0; j < 4; ++j) v[j] = scores[b * 256 + lane * 4 + j];
  int chosen = 0;
  for (int k = 0; k < 8; ++k) {
    float best = -3.4e38f; int bi = 0x7fffffff;
    #pragma unroll
    for (int j = 0; j < 4; ++j) {
      if (!(chosen & (1 << j))) {
        float s = v[j]; int n = lane * 4 + j;
        if (s > best || (s == best && n < bi)) { best = s; bi = n; }
      }
    }
    #pragma unroll
    for (int off = 32; off; off >>= 1) {
      float ob = __shfl_xor(best, off);
      int oi = __shfl_xor(bi, off);
      if (ob > best || (ob == best && oi < bi)) { best = ob; bi = oi; }
    }
    if ((bi >> 2) == lane) chosen |= 1 << (bi & 3);
    if (lane == 0) topi[b * 8 + k] = bi;
  }
}

// ---------------- 12) gather memory rows -> xg ----------------
__global__ __launch_bounds__(256) void k_gather(const float* __restrict__ q,
                                                const float* __restrict__ memv,
                                                const int* __restrict__ topi,
                                                const int* __restrict__ cont,
                                                const int* __restrict__ slot_b,
                                                const int* __restrict__ slot_start,
                                                const int* __restrict__ slot_cnt,
                                                float* __restrict__ xg) {
  int id = blockIdx.x * 256 + threadIdx.x;   // < 196608
  int d = id & 511;
  int rb = id >> 9;          // 0..383
  int b = rb / 192;
  int r = rb - b * 192;
  int p = r & 15;
  int slot = (r < 128) ? topi[b * 8 + (r >> 4)] : cont[(r - 128) >> 4];
  float val;
  int cnt = slot_cnt[slot];
  if (cnt > 0) {
    int ml = cnt < 16 ? cnt : 16;
    val = (p < ml) ? q[((size_t)(slot_b[slot] * 256 + slot_start[slot] + p)) * 512 + d] : 0.f;
  } else {
    val = memv[((size_t)slot * 16 + p) * 512 + d];
  }
  xg[id] = val;
}

// ---------------- 13) storage MLP ----------------
__global__ __launch_bounds__(256) void k_mlp1(const float* __restrict__ xg,
                                              const float* __restrict__ w1,
                                              const float* __restrict__ b1,
                                              float* __restrict__ h) {
  __shared__ float4 Qs4[512];
  __shared__ float4 Ws4[512];
  int n0 = blockIdx.x * 64, m0 = blockIdx.y * 64;
  float acc[4][4] = {};
  gemm64x64_k512(xg + (size_t)m0 * 512, w1 + (size_t)n0 * 512, acc, Qs4, Ws4);
  int t = threadIdx.x, tn = t & 15, tm = t >> 4;
  #pragma unroll
  for (int i = 0; i < 4; ++i) {
    int m = m0 + tm * 4 + i;
    #pragma unroll
    for (int j = 0; j < 4; ++j) {
      int n = n0 + tn * 4 + j;
      h[(size_t)m * 512 + n] = fmaxf(acc[i][j] + b1[n], 0.f);
    }
  }
}

__global__ __launch_bounds__(256) void k_mlp2(const float* __restrict__ h,
                                              const float* __restrict__ w2,
                                              const float* __restrict__ b2,
                                              float* __restrict__ out) {
  __shared__ float4 Qs4[512];
  __shared__ float4 Ws4[512];
  int n0 = blockIdx.x * 64, m0 = blockIdx.y * 64;
  float acc[4][4] = {};
  gemm64x64_k512(h + (size_t)m0 * 512, w2 + (size_t)n0 * 512, acc, Qs4, Ws4);
  int t = threadIdx.x, tn = t & 15, tm = t >> 4;
  #pragma unroll
  for (int i = 0; i < 4; ++i) {
    int m = m0 + tm * 4 + i;
    int b = (m >= 192) ? 1 : 0;
    int rr = m - b * 192;
    int n = n0 + tn * 4;
    float4 v = make_float4(acc[i][0] + b2[n], acc[i][1] + b2[n + 1],
                           acc[i][2] + b2[n + 2], acc[i][3] + b2[n + 3]);
    size_t base = OC1 + ((size_t)(b * 448 + rr)) * 512 + n;
    *(float4*)&out[base] = v;
    *(float4*)&out[base + NCTX] = v;
  }
}

// ---------------- 14) passthrough copies + mask ----------------
__global__ __launch_bounds__(256) void k_copy(const float* __restrict__ q,
                                              const float* __restrict__ key,
                                              const float* __restrict__ amask,
                                              float* __restrict__ out) {
  int id = blockIdx.x * 256 + threadIdx.x;
  if (id < 262144) { out[id] = q[id]; return; }
  if (id < 524288) {
    int id2 = id - 262144;
    int b = id2 >> 17;
    int s = (id2 >> 9) & 255;
    int d = id2 & 511;
    float v = key[id2];
    size_t p = OC1 + ((size_t)(b * 448 + 192 + s)) * 512 + d;
    out[p] = v;
    out[p + NCTX] = v;
    return;
  }
  if (id < 525184) {
    int j = id - 524288;   // 0..895
    int b = j / 448, c = j - b * 448;
    out[OMASK + j] = (c < 192) ? 1.0f : amask[b * 256 + (c - 192)];
  }
}

// ---------------- launch ----------------
extern "C" void kernel_launch(void* const* d_in, const int* in_sizes, int n_in,
                              void* d_out, int out_size, void* d_ws, size_t ws_size,
                              hipStream_t stream) {
  // Hard guard: if workspace is smaller than required, skip (harness will
  // report a clean mismatch instead of OOB-crashing the container).
  if (ws_size < WS_FLOATS_NEEDED * sizeof(float)) return;

  const float* q     = (const float*)d_in[0];
  const float* key   = (const float*)d_in[1];
  const float* amask = (const float*)d_in[3];
  const int*   tgt   = (const int*)d_in[4];
  const float* bw    = (const float*)d_in[5];
  const float* w1    = (const float*)d_in[6];
  const float* b1    = (const float*)d_in[7];
  const float* w2    = (const float*)d_in[8];
  const float* b2    = (const float*)d_in[9];
  const float* simw  = (const float*)d_in[10];
  const float* simb  = (const float*)d_in[11];
  const float* memk  = (const float*)d_in[12];
  const float* memv  = (const float*)d_in[13];
  const int*   meml  = (const int*)d_in[14];
  float* out = (float*)d_out;

  float* w = (float*)d_ws;
  float* p_partial = w;                      // 500*512 = 256000
  float* p_lse    = p_partial + 256000;      // 512
  float* p_sur    = p_lse + 512;             // 512
  float* p_sims   = p_sur + 512;             // 2*256*256 = 131072
  float* p_R      = p_sims + 131072;         // 2*256*257 = 131584
  float* p_deg    = p_R + 131584;            // 512
  float* p_qbar   = p_deg + 512;             // 1024
  float* p_qm     = p_qbar + 1024;           // 1024
  float* p_scores = p_qm + 1024;             // 512
  float* p_xg     = p_scores + 512;          // 2*192*512 = 196608
  float* p_h      = p_xg + 196608;           // 196608
  int* ip         = (int*)(p_h + 196608);
  int* ip_bnd     = ip;                      // 512
  int* ip_nseg    = ip + 512;                // 2
  int* ip_segst   = ip + 514;                // 514
  int* ip_segcnt  = ip + 1028;               // 514
  int* ip_slotb   = ip + 1542;               // 256
  int* ip_slotst  = ip + 1798;               // 256
  int* ip_slotcnt = ip + 2054;               // 256
  int* ip_topi    = ip + 2310;               // 16
  int* ip_cont    = ip + 2326;               // 4

  k_logits<<<dim3(500, 8), 256, 0, stream>>>(q, bw, p_partial);
  k_lse<<<2, 256, 0, stream>>>(p_partial, p_lse);
  k_zt<<<128, 256, 0, stream>>>(q, bw, tgt, p_lse, p_sur);
  k_bound<<<2, 256, 0, stream>>>(p_sur, ip_bnd);
  k_sims<<<dim3(4, 4, 2), 256, 0, stream>>>(q, p_sims);
  k_rowpref<<<128, 256, 0, stream>>>(p_sims, p_R, p_deg);
  k_refine<<<2, 256, 0, stream>>>(ip_bnd, p_R, p_deg, ip_nseg, ip_segst, ip_segcnt);
  k_slots<<<1, 256, 0, stream>>>(ip_nseg, ip_segst, ip_segcnt, meml,
                                 ip_slotb, ip_slotst, ip_slotcnt, ip_cont);
  k_qbar<<<4, 256, 0, stream>>>(q, p_qbar);
  k_qm<<<256, 256, 0, stream>>>(p_qbar, simw, simb, p_qm);
  k_scores<<<128, 256, 0, stream>>>(q, memk, meml, ip_slotb, ip_slotst, ip_slotcnt,
                                    p_qm, p_scores);
  k_topk<<<2, 64, 0, stream>>>(p_scores, ip_topi);
  k_gather<<<768, 256, 0, stream>>>(q, memv, ip_topi, ip_cont,
                                    ip_slotb, ip_slotst, ip_slotcnt, p_xg);
  k_mlp1<<<dim3(8, 6), 256, 0, stream>>>(p_xg, w1, b1, p_h);
  k_mlp2<<<dim3(8, 6), 256, 0, stream>>>(p_h, w2, b2, out);
  k_copy<<<2052, 256, 0, stream>>>(q, key, amask, out);
}

// Round 8
// 484.972 us; speedup vs baseline: 1.6372x; 1.2249x over previous
//
#include <hip/hip_runtime.h>

// ---------------- problem constants ----------------
constexpr int Bb = 2;
constexpr int Ss = 256;
constexpr int Dd = 512;
constexpr int Vv = 32000;
constexpr int NVB = Vv / 64;          // 500 v-bands (partial rows)
constexpr float GAMMA_C = 2.0f;
constexpr int MEMLEN = 16;
constexpr int NMEM = 256;
constexpr int MTOT = (8 + 4) * MEMLEN;   // 192
constexpr int CTXROWS = MTOT + Ss;       // 448

// output layout (floats)
constexpr size_t NQ   = (size_t)Bb * Ss * Dd;        // 262144
constexpr size_t OC1  = NQ;                          // 262144
constexpr size_t NCTX = (size_t)Bb * CTXROWS * Dd;   // 458752
constexpr size_t OC2  = OC1 + NCTX;                  // 720896
constexpr size_t OMASK = OC2 + NCTX;                 // 1179648

// workspace layout (floats); unchanged total ≈ 3.67 MB (pc aliases p_h)
constexpr size_t WS_FLOATS_NEEDED = 256000 + 512 + 512 + 131072 + 131584 + 512 +
                                    1024 + 1024 + 512 + 196608 + 196608 + 4096;

// ---------------- shared 64x64 fp32 GEMM core (K=512) — used by sims/mlp ----------
// acc[i][j] = sum_k A[tm*4+i][k] * B[tn*4+j][k]; XOR-swizzled LDS (bit-exact order)
__device__ __forceinline__ void gemm64x64_k512(const float* __restrict__ A,
                                               const float* __restrict__ Bm,
                                               float acc[4][4],
                                               float4* __restrict__ Qs4,
                                               float4* __restrict__ Ws4) {
  const int t = threadIdx.x;
  const int tn = t & 15, tm = t >> 4;
  float* __restrict__ Qf = (float*)Qs4;
  float* __restrict__ Wf = (float*)Ws4;
  #pragma unroll 2
  for (int kc = 0; kc < 512; kc += 32) {
    #pragma unroll
    for (int e = 0; e < 2; ++e) {
      const int idx4 = t + 256 * e;        // 0..511
      const int m = idx4 >> 3;             // 0..63
      const int kg = idx4 & 7;             // k-group
      const float4 qa = *(const float4*)(A + (size_t)m * 512 + kc + kg * 4);
      const float4 wb = *(const float4*)(Bm + (size_t)m * 512 + kc + kg * 4);
      const int fb = ((kg * 4) * 16 + ((m >> 2) ^ kg)) * 4 + (m & 3);
      Qf[fb]       = qa.x; Qf[fb + 64]  = qa.y;
      Qf[fb + 128] = qa.z; Qf[fb + 192] = qa.w;
      Wf[fb]       = wb.x; Wf[fb + 64]  = wb.y;
      Wf[fb + 128] = wb.z; Wf[fb + 192] = wb.w;
    }
    __syncthreads();
    #pragma unroll
    for (int k = 0; k < 32; ++k) {
      const int swz = (k >> 2) & 7;
      const float4 a4 = Qs4[k * 16 + (tm ^ swz)];
      const float4 b4 = Ws4[k * 16 + (tn ^ swz)];
      const float av[4] = {a4.x, a4.y, a4.z, a4.w};
      const float bv[4] = {b4.x, b4.y, b4.z, b4.w};
      #pragma unroll
      for (int i = 0; i < 4; ++i)
        #pragma unroll
        for (int j = 0; j < 4; ++j)
          acc[i][j] += av[i] * bv[j];
    }
    __syncthreads();
  }
}

// ---------------- 1) logits: 64x128 tile (2 bands), per-row band sum(exp) ----------
// Per-output FMA chain stays k-ascending; per-band epilogue partition identical to the
// old 64x64 kernel -> partial[] is BIT-EXACT vs the validated R7 anchor.
__global__ __launch_bounds__(256) void k_logits(const float* __restrict__ q,
                                                const float* __restrict__ bw,
                                                float* __restrict__ partial) {
  __shared__ float4 As4[512];    // 64 rows x 32 k (swizzled)
  __shared__ float4 Bs4[1024];   // 128 rows x 32 k (swizzled)
  __shared__ float red[64 * 17];
  const int bv = blockIdx.x;   // 0..249 (pair of 64-col bands)
  const int bm = blockIdx.y;   // 0..7
  const int t = threadIdx.x;
  const int tn = t & 15, tm = t >> 4;
  const float* A  = q  + (size_t)bm * 64 * 512;
  const float* Bm = bw + (size_t)bv * 128 * 512;
  float* Af = (float*)As4;
  float* Bf = (float*)Bs4;
  float acc0[4][4] = {};
  float acc1[4][4] = {};
  #pragma unroll 1
  for (int kc = 0; kc < 512; kc += 32) {
    #pragma unroll
    for (int e = 0; e < 2; ++e) {        // stage A: 512 float4
      const int idx = t + 256 * e;
      const int m = idx >> 3, kg = idx & 7;
      const float4 v = *(const float4*)(A + (size_t)m * 512 + kc + kg * 4);
      const int fb = ((kg * 4) * 16 + ((m >> 2) ^ kg)) * 4 + (m & 3);
      Af[fb] = v.x; Af[fb + 64] = v.y; Af[fb + 128] = v.z; Af[fb + 192] = v.w;
    }
    #pragma unroll
    for (int e = 0; e < 4; ++e) {        // stage B: 1024 float4
      const int idx = t + 256 * e;
      const int mB = idx >> 3, kg = idx & 7;
      const float4 v = *(const float4*)(Bm + (size_t)mB * 512 + kc + kg * 4);
      const int m4 = mB >> 2;
      const int g = (m4 & 24) | ((m4 & 7) ^ kg);
      const int fb = ((kg * 4) * 32 + g) * 4 + (mB & 3);
      Bf[fb] = v.x; Bf[fb + 128] = v.y; Bf[fb + 256] = v.z; Bf[fb + 384] = v.w;
    }
    __syncthreads();
    #pragma unroll
    for (int k = 0; k < 32; ++k) {
      const int swz = (k >> 2) & 7;
      const float4 a4 = As4[k * 16 + (tm ^ swz)];
      const int g0 = (tn & 8) | ((tn & 7) ^ swz);
      const float4 b0 = Bs4[k * 32 + g0];
      const float4 b1 = Bs4[k * 32 + 16 + g0];
      const float av[4]  = {a4.x, a4.y, a4.z, a4.w};
      const float b0v[4] = {b0.x, b0.y, b0.z, b0.w};
      const float b1v[4] = {b1.x, b1.y, b1.z, b1.w};
      #pragma unroll
      for (int i = 0; i < 4; ++i)
        #pragma unroll
        for (int j = 0; j < 4; ++j) {
          acc0[i][j] += av[i] * b0v[j];
          acc1[i][j] += av[i] * b1v[j];
        }
    }
    __syncthreads();
  }
  // epilogue band0 (identical partition/order as old kernel)
  #pragma unroll
  for (int i = 0; i < 4; ++i) {
    float s = 0.f;
    #pragma unroll
    for (int j = 0; j < 4; ++j) s += expf(acc0[i][j]);
    red[(tm * 4 + i) * 17 + tn] = s;
  }
  __syncthreads();
  if (t < 64) {
    float s = 0.f;
    #pragma unroll
    for (int j = 0; j < 16; ++j) s += red[t * 17 + j];
    partial[(size_t)(bv * 2) * 512 + bm * 64 + t] = s;
  }
  __syncthreads();
  // epilogue band1
  #pragma unroll
  for (int i = 0; i < 4; ++i) {
    float s = 0.f;
    #pragma unroll
    for (int j = 0; j < 4; ++j) s += expf(acc1[i][j]);
    red[(tm * 4 + i) * 17 + tn] = s;
  }
  __syncthreads();
  if (t < 64) {
    float s = 0.f;
    #pragma unroll
    for (int j = 0; j < 16; ++j) s += red[t * 17 + j];
    partial[(size_t)(bv * 2 + 1) * 512 + bm * 64 + t] = s;
  }
}

// ---------------- 2) fused misc: sims + qbar + lse-chunks + copy ----------------
constexpr int MISC_SIMS = 32;
constexpr int MISC_QBAR = MISC_SIMS + 4;     // 36
constexpr int MISC_LSE  = MISC_QBAR + 16;    // 52
constexpr int MISC_NBLK = MISC_LSE + 2052;   // 2104

__global__ __launch_bounds__(256) void k_misc(const float* __restrict__ q,
                                              const float* __restrict__ key,
                                              const float* __restrict__ amask,
                                              const float* __restrict__ partial,
                                              float* __restrict__ sims,
                                              float* __restrict__ qbar,
                                              double* __restrict__ pc,
                                              float* __restrict__ out) {
  __shared__ float4 sh4[1024];
  const int bx = blockIdx.x, t = threadIdx.x;
  if (bx < MISC_SIMS) {
    // sims = q q^T (64x64 tiles)
    int b = bx >> 4, rem = bx & 15;
    int m0 = (rem >> 2) * 64, n0 = (rem & 3) * 64;
    float acc[4][4] = {};
    const float* qb = q + (size_t)b * Ss * Dd;
    gemm64x64_k512(qb + (size_t)m0 * 512, qb + (size_t)n0 * 512, acc, sh4, sh4 + 512);
    int tn = t & 15, tm = t >> 4;
    float* outp = sims + (size_t)b * Ss * Ss;
    #pragma unroll
    for (int i = 0; i < 4; ++i) {
      float4 v = make_float4(acc[i][0], acc[i][1], acc[i][2], acc[i][3]);
      *(float4*)&outp[(size_t)(m0 + tm * 4 + i) * 256 + n0 + tn * 4] = v;
    }
  } else if (bx < MISC_QBAR) {
    int id = (bx - MISC_SIMS) * 256 + t;   // 0..1023
    int b = id >> 9, d = id & 511;
    float s = 0.f;
    for (int ss2 = 0; ss2 < 256; ++ss2) s += q[((size_t)(b * 256 + ss2)) * 512 + d];
    qbar[id] = s * (1.0f / 256.0f);
  } else if (bx < MISC_LSE) {
    // lse band-chunk partial sums (double, ascending j within chunk)
    int idx = bx - MISC_QBAR;   // 0..15
    int c = idx >> 1, rb = idx & 1;
    int r = rb * 256 + t;
    int j0 = c * 63, j1 = (j0 + 63 < NVB) ? j0 + 63 : NVB;
    double s = 0.0;
    for (int j = j0; j < j1; ++j) s += (double)partial[(size_t)j * 512 + r];
    pc[c * 512 + r] = s;
  } else {
    int id = (bx - MISC_LSE) * 256 + t;
    if (id < 262144) { out[id] = q[id]; return; }
    if (id < 524288) {
      int id2 = id - 262144;
      int b = id2 >> 17;
      int s = (id2 >> 9) & 255;
      int d = id2 & 511;
      float v = key[id2];
      size_t p = OC1 + ((size_t)(b * 448 + 192 + s)) * 512 + d;
      out[p] = v;
      out[p + NCTX] = v;
      return;
    }
    if (id < 525184) {
      int j = id - 524288;   // 0..895
      int b = j / 448, c = j - b * 448;
      out[OMASK + j] = (c < 192) ? 1.0f : amask[b * 256 + (c - 192)];
    }
  }
}

// ---------------- 3) sur = lse - z_target (wave/row; chunk-combine ascending) --------
__global__ __launch_bounds__(256) void k_sur(const float* __restrict__ q,
                                             const float* __restrict__ bw,
                                             const int* __restrict__ tgt,
                                             const double* __restrict__ pc,
                                             float* __restrict__ sur) {
  int wid = blockIdx.x * 4 + (threadIdx.x >> 6);  // 0..511
  int lane = threadIdx.x & 63;
  int tg = tgt[wid];
  const float* qp = q + (size_t)wid * 512;
  const float* wp = bw + (size_t)tg * 512;
  float a = 0.f;
  #pragma unroll
  for (int j = 0; j < 8; ++j) a += qp[lane + 64 * j] * wp[lane + 64 * j];
  #pragma unroll
  for (int off = 32; off; off >>= 1) a += __shfl_xor(a, off);
  if (lane == 0) {
    double s = 0.0;
    #pragma unroll
    for (int c = 0; c < 8; ++c) s += pc[c * 512 + wid];
    float lsef = (float)log(s);
    sur[wid] = lsef - a;
  }
}

// ---------------- 4) windowed threshold -> boundaries ----------------
__global__ __launch_bounds__(256) void k_bound(const float* __restrict__ sur,
                                               int* __restrict__ bnd) {
  __shared__ float ss[256];
  __shared__ float thrw[237];
  int b = blockIdx.x, t = threadIdx.x;
  ss[t] = sur[b * 256 + t];
  __syncthreads();
  if (t < 237) {
    float mn = 0.f;
    #pragma unroll
    for (int e = 0; e < 20; ++e) mn += ss[t + e];
    mn *= (1.0f / 20.0f);
    float v = 0.f;
    #pragma unroll
    for (int e = 0; e < 20; ++e) { float d = ss[t + e] - mn; v += d * d; }
    thrw[t] = mn + GAMMA_C * sqrtf(v * (1.0f / 19.0f));   // ddof=1
  }
  __syncthreads();
  float th = (t <= 18) ? thrw[0] : thrw[t - 19];
  bnd[b * 256 + t] = (ss[t] > th) ? 1 : 0;
}

// ---------------- 6) per-row prefix sums R[i][0..256] and deg ----------------
__global__ __launch_bounds__(256) void k_rowpref(const float* __restrict__ sims,
                                                 float* __restrict__ R,
                                                 float* __restrict__ deg) {
  int wid = blockIdx.x * 4 + (threadIdx.x >> 6);   // 0..511 (b*256+i)
  int lane = threadIdx.x & 63;
  int b = wid >> 8, i = wid & 255;
  const float* row = sims + (size_t)b * 65536 + (size_t)i * 256;
  float4 v = *(const float4*)&row[lane * 4];
  float c0 = v.x, c1 = c0 + v.y, c2 = c1 + v.z, c3 = c2 + v.w;
  float ls = c3;
  float sc = ls;
  for (int off = 1; off < 64; off <<= 1) {
    float u = __shfl_up(sc, off);
    if (lane >= off) sc += u;
  }
  float ex = sc - ls;
  float* Rr = R + (size_t)b * (256 * 257) + (size_t)i * 257;
  Rr[lane * 4 + 1] = ex + c0;
  Rr[lane * 4 + 2] = ex + c1;
  Rr[lane * 4 + 3] = ex + c2;
  Rr[lane * 4 + 4] = ex + c3;
  if (lane == 0) Rr[0] = 0.f;
  if (lane == 63) deg[b * 256 + i] = ex + c3;
}

// ---------------- 7) refine: per-row parallel terms + per-segment LDS sums ------------
// Segment sums keep ascending-i order per accumulator -> BIT-IDENTICAL to serial form.
__global__ __launch_bounds__(256) void k_refine(const int* __restrict__ bnd,
                                                const float* __restrict__ R,
                                                const float* __restrict__ deg,
                                                int* __restrict__ nseg,
                                                int* __restrict__ segstart_o,
                                                int* __restrict__ segcnt_o) {
  __shared__ int sb[256], lab[256];
  __shared__ int segst[258];
  __shared__ float Dc[257], Sc[257], Cr[257];
  __shared__ float degsh[256];
  __shared__ float Stm[256], Ctm[256];
  __shared__ float sh[6];   // tot tote Qun Csum curQ curC
  int b = blockIdx.x, t = threadIdx.x;
  sb[t] = bnd[b * 256 + t];
  degsh[t] = deg[b * 256 + t];
  for (int c = t; c < 258; c += 256) segst[c] = -1;
  __syncthreads();
  int a = 0;
  for (int i = 0; i <= t; ++i) a += sb[i];
  lab[t] = a;
  __syncthreads();
  if (t == 0 || lab[t - 1] != lab[t]) segst[lab[t]] = t;
  __syncthreads();
  int nb = lab[255];
  const float* Rb = R + (size_t)b * (256 * 257);
  // per-row terms (parallel over rows)
  {
    int c = lab[t];
    int a1 = segst[c];                               // always valid for row t
    int e1 = (c == nb) ? 255 : (segst[c + 1] - 1);
    const float* Rrow = Rb + (size_t)t * 257;
    Stm[t] = Rrow[e1 + 1] - Rrow[a1];
    float cv = 0.f;
    if (c < nb) {
      int a2 = segst[c + 1];
      int e2 = (c + 1 == nb) ? 255 : (segst[c + 2] - 1);
      cv = Rrow[e2 + 1] - Rrow[a2];
    }
    Ctm[t] = cv;
  }
  __syncthreads();
  // per-segment sums over LDS (ascending i)
  for (int c = t; c <= nb; c += 256) {
    float Dv = 0.f, Sv = 0.f, Cv = 0.f;
    int a1 = segst[c];
    if (a1 >= 0) {
      int e1 = (c == nb) ? 255 : (segst[c + 1] - 1);
      for (int i = a1; i <= e1; ++i) { Dv += degsh[i]; Sv += Stm[i]; Cv += Ctm[i]; }
    }
    Dc[c] = Dv; Sc[c] = Sv; Cr[c] = Cv;
  }
  __syncthreads();
  if (t == 0) {
    float tot = 0.f;
    for (int i = 0; i < 256; ++i) tot += degsh[i];
    float tote = tot + 1e-10f;
    float Qun = 0.f, Cs = 0.f;
    for (int c = 0; c <= nb; ++c) {
      Qun += Sc[c] - Dc[c] * Dc[c] / tote;
      Cs  += (Dc[c] - Sc[c]) / (fminf(Dc[c], tot - Dc[c]) + 1e-10f);
    }
    sh[0] = tot; sh[1] = tote; sh[2] = Qun; sh[3] = Cs;
    sh[4] = Qun / tote; sh[5] = Cs / (float)(nb + 1);
  }
  __syncthreads();
  int r = sb[t];
  if (r == 1) {
    float tot = sh[0], tote = sh[1], Qun = sh[2], Cs = sh[3], curQ = sh[4], curC = sh[5];
    int c2 = lab[t], c1 = c2 - 1;
    if (segst[c1] < 0) {
      // merging with empty label-0: Q bitwise-identical; C-sum identical, count drops by 1
      float newC0 = Cs / (float)nb;
      if (newC0 < curC) r = 0;
    } else {
      float D1 = Dc[c1], S1 = Sc[c1], D2 = Dc[c2], S2 = Sc[c2];
      float Dm = D1 + D2, Sm = S1 + S2 + 2.0f * Cr[c1];
      float tq1 = S1 - D1 * D1 / tote;
      float tq2 = S2 - D2 * D2 / tote;
      float tqm = Sm - Dm * Dm / tote;
      float newQ = (Qun - tq1 - tq2 + tqm) / tote;
      float tc1 = (D1 - S1) / (fminf(D1, tot - D1) + 1e-10f);
      float tc2 = (D2 - S2) / (fminf(D2, tot - D2) + 1e-10f);
      float tcm = (Dm - Sm) / (fminf(Dm, tot - Dm) + 1e-10f);
      float newC = (Cs - tc1 - tc2 + tcm) / (float)nb;
      if (newQ > curQ || newC < curC) r = 0;
    }
  }
  __syncthreads();
  sb[t] = r;
  __syncthreads();
  if (t == 0) {
    int ns = 0, st = 0;
    for (int i = 1; i <= 256; ++i) {
      if (i == 256 || sb[i] == 1) {
        segstart_o[b * 257 + ns] = st;
        segcnt_o[b * 257 + ns] = i - st;
        ns++;
        st = i;
      }
    }
    nseg[b] = ns;
  }
}

// ---------------- 8) slot assignment + continuity top-k (parallel, exact) ----------
__global__ __launch_bounds__(256) void k_slots(const int* __restrict__ nseg,
                                               const int* __restrict__ segstart_i,
                                               const int* __restrict__ segcnt_i,
                                               const int* __restrict__ meml_in,
                                               int* __restrict__ slot_b,
                                               int* __restrict__ slot_start,
                                               int* __restrict__ slot_cnt,
                                               int* __restrict__ cont) {
  __shared__ unsigned char validsh[256];
  __shared__ int ns01[2];
  int t = threadIdx.x;
  if (t < 2) ns01[t] = nseg[t];
  __syncthreads();
  int ns0 = ns01[0], total = ns0 + ns01[1];
  int rank = -1;
  for (int r = t; r < total; r += 256) rank = r;  // largest rank ≡ t (mod 256), < total
  int bb = 0, st = 0, ct = 0;
  if (rank >= 0) {
    bb = (rank >= ns0) ? 1 : 0;
    int s = rank - bb * ns0;
    st = segstart_i[bb * 257 + s];
    ct = segcnt_i[bb * 257 + s];
  }
  slot_b[t] = bb; slot_start[t] = st; slot_cnt[t] = ct;
  validsh[t] = (ct > 0 || meml_in[t] > 0) ? 1 : 0;
  __syncthreads();
  if (t == 0) {
    int k = 0;
    for (int n = 255; n >= 0 && k < 4; --n) if (validsh[n]) cont[k++] = n;
    for (int n = 0; n < 256 && k < 4; ++n) if (!validsh[n]) cont[k++] = n;
  }
}

// ---------------- 9) qm ----------------
__global__ __launch_bounds__(256) void k_qm(const float* __restrict__ qbar,
                                            const float* __restrict__ simw,
                                            const float* __restrict__ simb,
                                            float* __restrict__ qm) {
  int wid = blockIdx.x * 4 + (threadIdx.x >> 6);  // <1024
  int lane = threadIdx.x & 63;
  int b = wid >> 9, e = wid & 511;
  float a = 0.f;
  #pragma unroll
  for (int j = 0; j < 8; ++j)
    a += qbar[b * 512 + lane + 64 * j] * simw[(size_t)e * 512 + lane + 64 * j];
  #pragma unroll
  for (int off = 32; off; off >>= 1) a += __shfl_xor(a, off);
  if (lane == 0) qm[b * 512 + e] = a + simb[e];
}

// ---------------- 10) scores ----------------
__global__ __launch_bounds__(256) void k_scores(const float* __restrict__ q,
                                                const float* __restrict__ memk,
                                                const int* __restrict__ meml,
                                                const int* __restrict__ slot_b,
                                                const int* __restrict__ slot_start,
                                                const int* __restrict__ slot_cnt,
                                                const float* __restrict__ qm,
                                                float* __restrict__ scores) {
  int wid = blockIdx.x * 4 + (threadIdx.x >> 6);  // 0..511
  int lane = threadIdx.x & 63;
  int b = wid >> 8, n = wid & 255;
  const float* kp = nullptr;
  if (slot_cnt[n] > 0) kp = q + ((size_t)(slot_b[n] * 256 + slot_start[n])) * 512;
  else if (meml[n] > 0) kp = memk + (size_t)n * 512;
  float a = 0.f;
  if (kp) {
    #pragma unroll
    for (int j = 0; j < 8; ++j) a += qm[b * 512 + lane + 64 * j] * kp[lane + 64 * j];
    #pragma unroll
    for (int off = 32; off; off >>= 1) a += __shfl_xor(a, off);
  }
  if (lane == 0) scores[b * 256 + n] = kp ? a : -1000000000.0f;
}

// ---------------- 11) stable top-8 (parallel, exact tie-semantics) ----------------
__global__ __launch_bounds__(64) void k_topk(const float* __restrict__ scores,
                                             int* __restrict__ topi) {
  int b = blockIdx.x, lane = threadIdx.x;
  float v[4];
  #pragma unroll
  for (int j = 0; j < 4; ++j) v[j] = scores[b * 256 + lane * 4 + j];
  int chosen = 0;
  for (int k = 0; k < 8; ++k) {
    float best = -3.4e38f; int bi = 0x7fffffff;
    #pragma unroll
    for (int j = 0; j < 4; ++j) {
      if (!(chosen & (1 << j))) {
        float s = v[j]; int n = lane * 4 + j;
        if (s > best || (s == best && n < bi)) { best = s; bi = n; }
      }
    }
    #pragma unroll
    for (int off = 32; off; off >>= 1) {
      float ob = __shfl_xor(best, off);
      int oi = __shfl_xor(bi, off);
      if (ob > best || (ob == best && oi < bi)) { best = ob; bi = oi; }
    }
    if ((bi >> 2) == lane) chosen |= 1 << (bi & 3);
    if (lane == 0) topi[b * 8 + k] = bi;
  }
}

// ---------------- 12) gather memory rows -> xg ----------------
__global__ __launch_bounds__(256) void k_gather(const float* __restrict__ q,
                                                const float* __restrict__ memv,
                                                const int* __restrict__ topi,
                                                const int* __restrict__ cont,
                                                const int* __restrict__ slot_b,
                                                const int* __restrict__ slot_start,
                                                const int* __restrict__ slot_cnt,
                                                float* __restrict__ xg) {
  int id = blockIdx.x * 256 + threadIdx.x;   // < 196608
  int d = id & 511;
  int rb = id >> 9;          // 0..383
  int b = rb / 192;
  int r = rb - b * 192;
  int p = r & 15;
  int slot = (r < 128) ? topi[b * 8 + (r >> 4)] : cont[(r - 128) >> 4];
  float val;
  int cnt = slot_cnt[slot];
  if (cnt > 0) {
    int ml = cnt < 16 ? cnt : 16;
    val = (p < ml) ? q[((size_t)(slot_b[slot] * 256 + slot_start[slot] + p)) * 512 + d] : 0.f;
  } else {
    val = memv[((size_t)slot * 16 + p) * 512 + d];
  }
  xg[id] = val;
}

// ---------------- 13) storage MLP ----------------
__global__ __launch_bounds__(256) void k_mlp1(const float* __restrict__ xg,
                                              const float* __restrict__ w1,
                                              const float* __restrict__ b1,
                                              float* __restrict__ h) {
  __shared__ float4 Qs4[512];
  __shared__ float4 Ws4[512];
  int n0 = blockIdx.x * 64, m0 = blockIdx.y * 64;
  float acc[4][4] = {};
  gemm64x64_k512(xg + (size_t)m0 * 512, w1 + (size_t)n0 * 512, acc, Qs4, Ws4);
  int t = threadIdx.x, tn = t & 15, tm = t >> 4;
  #pragma unroll
  for (int i = 0; i < 4; ++i) {
    int m = m0 + tm * 4 + i;
    #pragma unroll
    for (int j = 0; j < 4; ++j) {
      int n = n0 + tn * 4 + j;
      h[(size_t)m * 512 + n] = fmaxf(acc[i][j] + b1[n], 0.f);
    }
  }
}

__global__ __launch_bounds__(256) void k_mlp2(const float* __restrict__ h,
                                              const float* __restrict__ w2,
                                              const float* __restrict__ b2,
                                              float* __restrict__ out) {
  __shared__ float4 Qs4[512];
  __shared__ float4 Ws4[512];
  int n0 = blockIdx.x * 64, m0 = blockIdx.y * 64;
  float acc[4][4] = {};
  gemm64x64_k512(h + (size_t)m0 * 512, w2 + (size_t)n0 * 512, acc, Qs4, Ws4);
  int t = threadIdx.x, tn = t & 15, tm = t >> 4;
  #pragma unroll
  for (int i = 0; i < 4; ++i) {
    int m = m0 + tm * 4 + i;
    int b = (m >= 192) ? 1 : 0;
    int rr = m - b * 192;
    int n = n0 + tn * 4;
    float4 v = make_float4(acc[i][0] + b2[n], acc[i][1] + b2[n + 1],
                           acc[i][2] + b2[n + 2], acc[i][3] + b2[n + 3]);
    size_t base = OC1 + ((size_t)(b * 448 + rr)) * 512 + n;
    *(float4*)&out[base] = v;
    *(float4*)&out[base + NCTX] = v;
  }
}

// ---------------- launch ----------------
extern "C" void kernel_launch(void* const* d_in, const int* in_sizes, int n_in,
                              void* d_out, int out_size, void* d_ws, size_t ws_size,
                              hipStream_t stream) {
  if (ws_size < WS_FLOATS_NEEDED * sizeof(float)) return;

  const float* q     = (const float*)d_in[0];
  const float* key   = (const float*)d_in[1];
  const float* amask = (const float*)d_in[3];
  const int*   tgt   = (const int*)d_in[4];
  const float* bw    = (const float*)d_in[5];
  const float* w1    = (const float*)d_in[6];
  const float* b1    = (const float*)d_in[7];
  const float* w2    = (const float*)d_in[8];
  const float* b2    = (const float*)d_in[9];
  const float* simw  = (const float*)d_in[10];
  const float* simb  = (const float*)d_in[11];
  const float* memk  = (const float*)d_in[12];
  const float* memv  = (const float*)d_in[13];
  const int*   meml  = (const int*)d_in[14];
  float* out = (float*)d_out;

  float* w = (float*)d_ws;
  float* p_partial = w;                      // 500*512 = 256000
  float* p_lse    = p_partial + 256000;      // 512 (unused, layout keep)
  float* p_sur    = p_lse + 512;             // 512
  float* p_sims   = p_sur + 512;             // 131072
  float* p_R      = p_sims + 131072;         // 131584
  float* p_deg    = p_R + 131584;            // 512
  float* p_qbar   = p_deg + 512;             // 1024
  float* p_qm     = p_qbar + 1024;           // 1024
  float* p_scores = p_qm + 1024;             // 512
  float* p_xg     = p_scores + 512;          // 196608
  float* p_h      = p_xg + 196608;           // 196608
  double* p_pc    = (double*)p_h;            // 8*512 doubles, consumed before mlp1 writes h
  int* ip         = (int*)(p_h + 196608);
  int* ip_bnd     = ip;                      // 512
  int* ip_nseg    = ip + 512;                // 2
  int* ip_segst   = ip + 514;                // 514
  int* ip_segcnt  = ip + 1028;               // 514
  int* ip_slotb   = ip + 1542;               // 256
  int* ip_slotst  = ip + 1798;               // 256
  int* ip_slotcnt = ip + 2054;               // 256
  int* ip_topi    = ip + 2310;               // 16
  int* ip_cont    = ip + 2326;               // 4

  k_logits<<<dim3(250, 8), 256, 0, stream>>>(q, bw, p_partial);
  k_misc<<<MISC_NBLK, 256, 0, stream>>>(q, key, amask, p_partial,
                                        p_sims, p_qbar, p_pc, out);
  k_sur<<<128, 256, 0, stream>>>(q, bw, tgt, p_pc, p_sur);
  k_bound<<<2, 256, 0, stream>>>(p_sur, ip_bnd);
  k_rowpref<<<128, 256, 0, stream>>>(p_sims, p_R, p_deg);
  k_refine<<<2, 256, 0, stream>>>(ip_bnd, p_R, p_deg, ip_nseg, ip_segst, ip_segcnt);
  k_slots<<<1, 256, 0, stream>>>(ip_nseg, ip_segst, ip_segcnt, meml,
                                 ip_slotb, ip_slotst, ip_slotcnt, ip_cont);
  k_qm<<<256, 256, 0, stream>>>(p_qbar, simw, simb, p_qm);
  k_scores<<<128, 256, 0, stream>>>(q, memk, meml, ip_slotb, ip_slotst, ip_slotcnt,
                                    p_qm, p_scores);
  k_topk<<<2, 64, 0, stream>>>(p_scores, ip_topi);
  k_gather<<<768, 256, 0, stream>>>(q, memv, ip_topi, ip_cont,
                                    ip_slotb, ip_slotst, ip_slotcnt, p_xg);
  k_mlp1<<<dim3(8, 6), 256, 0, stream>>>(p_xg, w1, b1, p_h);
  k_mlp2<<<dim3(8, 6), 256, 0, stream>>>(p_h, w2, b2, out);
}